// Round 12
// baseline (375.351 us; speedup 1.0000x reference)
//
#include <hip/hip_runtime.h>

typedef __bf16 bf16x8 __attribute__((ext_vector_type(8)));
typedef float f32x4 __attribute__((ext_vector_type(4)));
typedef float f32x16 __attribute__((ext_vector_type(16)));

#define B_SZ 4
#define S_SZ 4096
#define D_SZ 1024
#define ELEMS_MAT ((size_t)B_SZ * S_SZ * D_SZ)   // 16,777,216

// ---- workspace layout (ushort elems), footprint <= proven 174 MB ----
#define OFF_Q  ((size_t)0)
#define OFF_K  (ELEMS_MAT)
#define OFF_VT (2 * ELEMS_MAT)
#define ZONE   (3 * ELEMS_MAT)
#define OFF_XB (ZONE)
#define OFF_WT (ZONE + 2 * ELEMS_MAT)
#define OFF_S  (ZONE)                             // aliases xb+Wt (dead by then)
#define S_BATCH ((size_t)8912896)                 // 136 tiles * 256*256
#define OFF_LP (ZONE + 4 * S_BATCH)               // [17][16384] f32 sumexp partials

#define MFMA32(a, b, c) __builtin_amdgcn_mfma_f32_32x32x16_bf16((a), (b), (c), 0, 0, 0)

static __device__ __forceinline__ unsigned short f2bf(float f) {
  __bf16 h = (__bf16)f;
  return __builtin_bit_cast(unsigned short, h);
}
static __device__ __forceinline__ float Ef(float x) {   // e^x via v_exp_f32
  return __builtin_exp2f(x * 1.44269504f);
}

static __device__ __forceinline__ void async_lds16(const void* g, void* l) {
  __builtin_amdgcn_global_load_lds((__attribute__((address_space(1))) void*)g,
                                   (__attribute__((address_space(3))) void*)l, 16, 0, 0);
}

// ---------------- cast x (fp32 -> bf16) ----------------
__global__ void cast_x_kernel(const float* __restrict__ x, unsigned short* __restrict__ xb) {
  size_t i = ((size_t)blockIdx.x * 256 + threadIdx.x) * 8;
  f32x4 a = *(const f32x4*)(x + i);
  f32x4 b = *(const f32x4*)(x + i + 4);
  bf16x8 o;
  o[0] = (__bf16)a[0]; o[1] = (__bf16)a[1]; o[2] = (__bf16)a[2]; o[3] = (__bf16)a[3];
  o[4] = (__bf16)b[0]; o[5] = (__bf16)b[1]; o[6] = (__bf16)b[2]; o[7] = (__bf16)b[3];
  *(bf16x8*)(xb + i) = o;
}

// ---------------- transpose-cast weights: Wt[n][k] = bf16(W[k][n]); Wt = [3072][1024] ----------------
__global__ void cast_wt_kernel(const float* __restrict__ Wq, const float* __restrict__ Wk,
                               const float* __restrict__ Wv, unsigned short* __restrict__ Wt) {
  __shared__ float tl[64][65];
  const float* W = blockIdx.z == 0 ? Wq : (blockIdx.z == 1 ? Wk : Wv);
  unsigned short* out = Wt + (size_t)blockIdx.z * (size_t)D_SZ * (size_t)D_SZ;
  const int k0 = blockIdx.x * 64, n0 = blockIdx.y * 64;
  const int t = threadIdx.x;
  for (int i = t; i < 4096; i += 256) {
    int r = i >> 6, c = i & 63;
    tl[r][c] = W[(size_t)(k0 + r) * D_SZ + n0 + c];
  }
  __syncthreads();
  for (int i = t; i < 4096; i += 256) {
    int r = i >> 6, c = i & 63;
    out[(size_t)(n0 + r) * D_SZ + k0 + c] = f2bf(tl[c][r]);
  }
}

// ================= 32x32x16-MFMA GEMM, [rows][64 bf16] LDS (128B rows) =================
// swizzle: 16B slot ^= (row&7); staged linear-dest with slot-permuted source (m173/m201).
static __device__ __forceinline__ void stage_tile256(const char* src, size_t ld, char* lds, int tid) {
#pragma unroll
  for (int it = 0; it < 4; ++it) {
    int i = it * 512 + tid;             // 2048 chunks of 16B = [256][64]
    int row = i >> 3, slot = i & 7;
    int s = slot ^ (row & 7);
    async_lds16(src + (size_t)row * ld + s * 16, lds + i * 16);
  }
}
static __device__ __forceinline__ void stage_tile128(const char* src, size_t ld, char* lds, int tid) {
#pragma unroll
  for (int it = 0; it < 2; ++it) {
    int i = it * 512 + tid;             // 1024 chunks = [128][64]
    int row = i >> 3, slot = i & 7;
    int s = slot ^ (row & 7);
    async_lds16(src + (size_t)row * ld + s * 16, lds + i * 16);
  }
}

// frag read for 32x32x16: lane l reads row (base + (l&31)), 8 bf16 at k = kc*16 + (l>>5)*8
static __device__ __forceinline__ bf16x8 lds_frag32(const char* base, int row, int kc, int kh) {
  const int slot = kc * 2 + kh;
  return *(const bf16x8*)(base + row * 128 + ((slot ^ (row & 7)) << 4));
}

// ---- BM=BN=256, BK=64, 8 waves (2M x 4N), wave-tile 128x64. acc f32x16[4][2]. ----
static __device__ __forceinline__ void ml32_256(const char* A, size_t lda,
                                                const char* B, size_t ldb, int NT,
                                                char smA[2][32768], char smB[2][32768],
                                                int tid, f32x16 acc[4][2]) {
  const int lane = tid & 63, w = tid >> 6;
  const int wm = w >> 2, wn = w & 3, l31 = lane & 31, kh = lane >> 5;
  stage_tile256(A, lda, smA[0], tid);
  stage_tile256(B, ldb, smB[0], tid);
  for (int t = 0; t < NT; ++t) {
    const int d = t & 1;
    const bool pre = (t + 1 < NT);
    if (pre) {
      stage_tile256(A + (size_t)(t + 1) * 128, lda, smA[d ^ 1], tid);
      stage_tile256(B + (size_t)(t + 1) * 128, ldb, smB[d ^ 1], tid);
      asm volatile("s_waitcnt vmcnt(8)" ::: "memory");   // tile t fully landed
    } else {
      asm volatile("s_waitcnt vmcnt(0)" ::: "memory");
    }
    __builtin_amdgcn_s_barrier();
#pragma unroll
    for (int kc = 0; kc < 4; ++kc) {
      bf16x8 bfr[2], af[4];
#pragma unroll
      for (int g = 0; g < 2; ++g) bfr[g] = lds_frag32(smB[d], wn * 64 + g * 32 + l31, kc, kh);
#pragma unroll
      for (int mi = 0; mi < 4; ++mi) af[mi] = lds_frag32(smA[d], wm * 128 + mi * 32 + l31, kc, kh);
      __builtin_amdgcn_s_setprio(1);
#pragma unroll
      for (int mi = 0; mi < 4; ++mi)
#pragma unroll
        for (int g = 0; g < 2; ++g) acc[mi][g] = MFMA32(af[mi], bfr[g], acc[mi][g]);
      __builtin_amdgcn_s_setprio(0);
    }
    __builtin_amdgcn_s_barrier();
  }
}

// ---- BM=256, BN=128, BK=64, 8 waves (4M x 2N), wave-tile 64x64. acc f32x16[2][2]. ----
static __device__ __forceinline__ void ml32_pv(const char* A, size_t lda,
                                               const char* B, size_t ldb, int NT,
                                               char smA[2][32768], char smB[2][16384],
                                               int tid, f32x16 acc[2][2]) {
  const int lane = tid & 63, w = tid >> 6;
  const int wm = w >> 1, wn = w & 1, l31 = lane & 31, kh = lane >> 5;
  stage_tile256(A, lda, smA[0], tid);
  stage_tile128(B, ldb, smB[0], tid);
  for (int t = 0; t < NT; ++t) {
    const int d = t & 1;
    const bool pre = (t + 1 < NT);
    if (pre) {
      stage_tile256(A + (size_t)(t + 1) * 128, lda, smA[d ^ 1], tid);
      stage_tile128(B + (size_t)(t + 1) * 128, ldb, smB[d ^ 1], tid);
      asm volatile("s_waitcnt vmcnt(6)" ::: "memory");
    } else {
      asm volatile("s_waitcnt vmcnt(0)" ::: "memory");
    }
    __builtin_amdgcn_s_barrier();
#pragma unroll
    for (int kc = 0; kc < 4; ++kc) {
      bf16x8 bfr[2], af[2];
#pragma unroll
      for (int g = 0; g < 2; ++g) bfr[g] = lds_frag32(smB[d], wn * 64 + g * 32 + l31, kc, kh);
#pragma unroll
      for (int mi = 0; mi < 2; ++mi) af[mi] = lds_frag32(smA[d], wm * 64 + mi * 32 + l31, kc, kh);
      __builtin_amdgcn_s_setprio(1);
#pragma unroll
      for (int mi = 0; mi < 2; ++mi)
#pragma unroll
        for (int g = 0; g < 2; ++g) acc[mi][g] = MFMA32(af[mi], bfr[g], acc[mi][g]);
      __builtin_amdgcn_s_setprio(0);
    }
    __builtin_amdgcn_s_barrier();
  }
}

// C/D mapping (verified m74/m101): col = lane&31, row = (reg&3) + 8*(reg>>2) + 4*(lane>>5)

// ---------------- QKV: [16384,1024] x [1024,3072]; V written transposed ----------------
__global__ __launch_bounds__(512, 2) void gemm_qkv256(const unsigned short* __restrict__ xb,
                                                      const unsigned short* __restrict__ Wt,
                                                      unsigned short* __restrict__ Q,
                                                      unsigned short* __restrict__ K,
                                                      unsigned short* __restrict__ Vt) {
  __shared__ char smA[2][32768];
  __shared__ char smB[2][32768];
  const int tid = threadIdx.x;
  f32x16 acc[4][2];
#pragma unroll
  for (int mi = 0; mi < 4; ++mi)
#pragma unroll
    for (int g = 0; g < 2; ++g)
#pragma unroll
      for (int e = 0; e < 16; ++e) acc[mi][g][e] = 0.f;
  const int bid = blockIdx.x;
  const int sw = (bid & 7) * 96 + (bid >> 3);   // XCD swizzle (768 = 8*96)
  const int mt = sw / 12, nt = sw % 12;         // 12 consecutive (one XCD) share A panel
  const char* A = (const char*)xb + (size_t)mt * 256 * 2048;
  const char* Bp = (const char*)Wt + (size_t)nt * 256 * 2048;
  ml32_256(A, 2048, Bp, 2048, 16, smA, smB, tid, acc);
  const int lane = tid & 63, w = tid >> 6;
  const int wm = w >> 2, wn = w & 3;
  const int l31 = lane & 31, kh = lane >> 5;
  if (nt < 8) {
    unsigned short* Out = (nt >> 2) == 0 ? Q : K;
    const int nb = (nt & 3) * 256;
#pragma unroll
    for (int mi = 0; mi < 4; ++mi)
#pragma unroll
      for (int g = 0; g < 2; ++g)
#pragma unroll
        for (int q = 0; q < 4; ++q)
#pragma unroll
          for (int j = 0; j < 4; ++j) {
            const int m = mt * 256 + wm * 128 + mi * 32 + 8 * q + 4 * kh + j;
            const int n = nb + wn * 64 + g * 32 + l31;
            Out[(size_t)m * D_SZ + n] = f2bf(acc[mi][g][q * 4 + j]);
          }
  } else {
    // V: write transposed Vt[b][d][s]; 4 consecutive s per store (8 B)
#pragma unroll
    for (int mi = 0; mi < 4; ++mi)
#pragma unroll
      for (int g = 0; g < 2; ++g)
#pragma unroll
        for (int q = 0; q < 4; ++q) {
          const int m = mt * 256 + wm * 128 + mi * 32 + 8 * q + 4 * kh;
          const int n = (nt - 8) * 256 + wn * 64 + g * 32 + l31;
          const int b = m >> 12, s = m & 4095;
          ushort4 pk;
          pk.x = f2bf(acc[mi][g][q * 4 + 0]); pk.y = f2bf(acc[mi][g][q * 4 + 1]);
          pk.z = f2bf(acc[mi][g][q * 4 + 2]); pk.w = f2bf(acc[mi][g][q * 4 + 3]);
          *(ushort4*)(Vt + (size_t)b * (D_SZ * S_SZ) + (size_t)n * S_SZ + s) = pk;
        }
  }
}

// ---------------- S-pass, mixed granularity: 64 half-tiles (first) + 512 full tiles ----
// P' = exp((QK^T)/32) masked; per-row sumexp partials into lp[J] (halves: odd->slot16 atomic).
__global__ __launch_bounds__(512, 2) void s_gemm_mixed(const unsigned short* __restrict__ Q,
                                                       const unsigned short* __restrict__ K,
                                                       unsigned short* __restrict__ Sp,
                                                       float* __restrict__ lp) {
  __shared__ char smA[2][32768];
  __shared__ char smB[2][32768];
  const int tid = threadIdx.x;
  const int bid = blockIdx.x;
  const int lane = tid & 63, w = tid >> 6;
  const int l31 = lane & 31, kh = lane >> 5;

  if (bid < 64) {
    // ======== half-tile path: BN=128, tiles 512..543 (batch 3, I>=13) ========
    const int hid = (bid & 7) * 8 + (bid >> 3);     // bijective, xcd = bid&7
    const int t = 104 + (hid >> 1);                 // tile-in-batch3: 104..135
    const int parity = hid & 1;
    int I = 13;
    while ((I + 1) * (I + 2) / 2 <= t) ++I;
    const int J = t - I * (I + 1) / 2;
    const int Jh = 2 * J + parity;
    const int b = 3;
    f32x16 acc[2][2];
#pragma unroll
    for (int mi = 0; mi < 2; ++mi)
#pragma unroll
      for (int g = 0; g < 2; ++g)
#pragma unroll
        for (int e = 0; e < 16; ++e) acc[mi][g][e] = 0.f;
    const char* A = (const char*)Q + ((size_t)b * S_SZ + (size_t)I * 256) * 2048;
    const char* Bp = (const char*)K + ((size_t)b * S_SZ + (size_t)Jh * 128) * 2048;
    ml32_pv(A, 2048, Bp, 2048, 16, smA, (char (*)[16384])smB, tid, acc);
    const int wm = w >> 1, wn = w & 1;
    const int L = (I + 1) * 256;
    unsigned short* So = Sp + (size_t)b * S_BATCH + (size_t)(I * (I + 1) / 2) * 65536;
    float* shl = (float*)smB;          // 2 KB scratch, loop drained
    __syncthreads();
#pragma unroll
    for (int mi = 0; mi < 2; ++mi) {
#pragma unroll
      for (int q = 0; q < 4; ++q)
#pragma unroll
        for (int j = 0; j < 4; ++j) {
          const int m = wm * 64 + mi * 32 + 8 * q + 4 * kh + j;
          float se = 0.f;
#pragma unroll
          for (int g = 0; g < 2; ++g) {
            const int nG = Jh * 128 + wn * 64 + g * 32 + l31;
            float v = acc[mi][g][q * 4 + j] * 0.03125f;
            if (nG > I * 256 + m) v = -1e30f;
            float ev = Ef(v);
            So[(size_t)m * L + nG] = f2bf(ev);
            se += ev;
          }
          se += __shfl_xor(se, 1);
          se += __shfl_xor(se, 2);
          se += __shfl_xor(se, 4);
          se += __shfl_xor(se, 8);
          se += __shfl_xor(se, 16);
          if (l31 == 0) shl[wn * 256 + m] = se;
        }
    }
    __syncthreads();
    if (tid < 256) {
      float ll = shl[tid] + shl[256 + tid];
      const int r = b * 4096 + I * 256 + tid;
      if (parity == 0) lp[J * 16384 + r] = ll;
      else atomicAdd(lp + 16 * 16384 + r, ll);
    }
  } else {
    // ======== full-tile path: 256x256, tile ids 0..511 ========
    f32x16 acc[4][2];
#pragma unroll
    for (int mi = 0; mi < 4; ++mi)
#pragma unroll
      for (int g = 0; g < 2; ++g)
#pragma unroll
        for (int e = 0; e < 16; ++e) acc[mi][g][e] = 0.f;
    const int fid = bid - 64;
    const int sw = (fid & 7) * 64 + (fid >> 3);   // bijective over 512
    const int b = sw / 136;
    const int tile = sw % 136;
    int I = (int)((sqrtf(8.0f * tile + 1.0f) - 1.0f) * 0.5f);
    while ((I + 1) * (I + 2) / 2 <= tile) ++I;
    while (I * (I + 1) / 2 > tile) --I;
    const int J = tile - I * (I + 1) / 2;
    const char* A = (const char*)Q + ((size_t)b * S_SZ + (size_t)I * 256) * 2048;
    const char* Bp = (const char*)K + ((size_t)b * S_SZ + (size_t)J * 256) * 2048;
    ml32_256(A, 2048, Bp, 2048, 16, smA, smB, tid, acc);
    const int wm = w >> 2, wn = w & 3;
    const int L = (I + 1) * 256;
    unsigned short* So = Sp + (size_t)b * S_BATCH + (size_t)(I * (I + 1) / 2) * 65536;
    float* shl = (float*)smA;           // [4 wn][256 rows] partials (loop drained)
    __syncthreads();
#pragma unroll
    for (int mi = 0; mi < 4; ++mi) {
#pragma unroll
      for (int q = 0; q < 4; ++q)
#pragma unroll
        for (int j = 0; j < 4; ++j) {
          const int m = wm * 128 + mi * 32 + 8 * q + 4 * kh + j;
          float se = 0.f;
#pragma unroll
          for (int g = 0; g < 2; ++g) {
            const int n = J * 256 + wn * 64 + g * 32 + l31;
            float v = acc[mi][g][q * 4 + j] * 0.03125f;
            if (n > I * 256 + m) v = -1e30f;
            float ev = Ef(v);
            So[(size_t)m * L + n] = f2bf(ev);
            se += ev;
          }
          se += __shfl_xor(se, 1);
          se += __shfl_xor(se, 2);
          se += __shfl_xor(se, 4);
          se += __shfl_xor(se, 8);
          se += __shfl_xor(se, 16);
          if (l31 == 0) shl[wn * 256 + m] = se;
        }
    }
    __syncthreads();
    if (tid < 256) {
      float ll = shl[tid] + shl[256 + tid] + shl[512 + tid] + shl[768 + tid];
      lp[J * 16384 + b * 4096 + I * 256 + tid] = ll;
    }
  }
}

// ---------------- sum partials -> slot0 holds 1/l per row ----------------
__global__ __launch_bounds__(256) void sum_stats(float* __restrict__ lp) {
  const int r = blockIdx.x * 256 + threadIdx.x;    // 16384 rows
  const int I = (r & 4095) >> 8;
  float l = 0.f;
  for (int J = 0; J <= I; ++J) l += lp[J * 16384 + r];
  if (r >= 15616) l += lp[16 * 16384 + r];         // b=3, I>=13: odd-half partials
  lp[r] = 1.0f / l;
}

// ---------------- O = P' V * rl, paired row-blocks (68 K-steps, uniform) ----------------
__global__ __launch_bounds__(512, 2) void pv_bal(const unsigned short* __restrict__ Sp,
                                                 const unsigned short* __restrict__ Vt,
                                                 const float* __restrict__ lp,
                                                 float* __restrict__ out) {
  __shared__ char smA[2][32768];
  __shared__ char smB[2][16384];
  const int tid = threadIdx.x;
  const int bid = blockIdx.x;
  const int sw = (bid & 7) * 32 + (bid >> 3);   // 256 = 8*32, bijective
  const int p = sw >> 5, b = (sw >> 3) & 3, nt = sw & 7;
  const int lane = tid & 63, w = tid >> 6;
  const int wm = w >> 1, wn = w & 1;
  const int l31 = lane & 31, kh = lane >> 5;
  f32x16 acc[2][2];
#pragma unroll
  for (int half = 0; half < 2; ++half) {
    const int I = half ? (15 - p) : p;
#pragma unroll
    for (int mi = 0; mi < 2; ++mi)
#pragma unroll
      for (int g = 0; g < 2; ++g)
#pragma unroll
        for (int e = 0; e < 16; ++e) acc[mi][g][e] = 0.f;
    const char* A = (const char*)(Sp + (size_t)b * S_BATCH + (size_t)(I * (I + 1) / 2) * 65536);
    const size_t lda = (size_t)(I + 1) * 512;   // bytes
    const char* Bp = (const char*)Vt + ((size_t)b * D_SZ + (size_t)nt * 128) * (S_SZ * 2);
    ml32_pv(A, lda, Bp, S_SZ * 2, (I + 1) * 4, smA, smB, tid, acc);
#pragma unroll
    for (int mi = 0; mi < 2; ++mi)
#pragma unroll
      for (int q = 0; q < 4; ++q)
#pragma unroll
        for (int j = 0; j < 4; ++j) {
          const int m = wm * 64 + mi * 32 + 8 * q + 4 * kh + j;
          const float rl = lp[b * 4096 + I * 256 + m];
#pragma unroll
          for (int g = 0; g < 2; ++g) {
            const int n = nt * 128 + wn * 64 + g * 32 + l31;
            out[((size_t)b * S_SZ + (size_t)I * 256 + m) * D_SZ + n] = acc[mi][g][q * 4 + j] * rl;
          }
        }
    __syncthreads();
  }
}

extern "C" void kernel_launch(void* const* d_in, const int* in_sizes, int n_in,
                              void* d_out, int out_size, void* d_ws, size_t ws_size,
                              hipStream_t stream) {
  (void)in_sizes; (void)n_in; (void)out_size; (void)ws_size;
  const float* x  = (const float*)d_in[0];
  const float* Wq = (const float*)d_in[1];
  const float* Wk = (const float*)d_in[2];
  const float* Wv = (const float*)d_in[3];
  float* out = (float*)d_out;
  unsigned short* ws = (unsigned short*)d_ws;
  float* lp = (float*)(ws + OFF_LP);

  cast_x_kernel<<<8192, 256, 0, stream>>>(x, ws + OFF_XB);
  cast_wt_kernel<<<dim3(16, 16, 3), 256, 0, stream>>>(Wq, Wk, Wv, ws + OFF_WT);
  gemm_qkv256<<<768, 512, 0, stream>>>(ws + OFF_XB, ws + OFF_WT,
                                       ws + OFF_Q, ws + OFF_K, ws + OFF_VT);
  hipMemsetAsync(lp + 16 * 16384, 0, 16384 * sizeof(float), stream);  // slot16 accum
  s_gemm_mixed<<<576, 512, 0, stream>>>(ws + OFF_Q, ws + OFF_K, ws + OFF_S, lp);
  sum_stats<<<64, 256, 0, stream>>>(lp);
  pv_bal<<<256, 512, 0, stream>>>(ws + OFF_S, ws + OFF_VT, lp, out);
}

// Round 13
// 341.632 us; speedup vs baseline: 1.0987x; 1.0987x over previous
//
#include <hip/hip_runtime.h>

typedef __bf16 bf16x8 __attribute__((ext_vector_type(8)));
typedef float f32x4 __attribute__((ext_vector_type(4)));

#define B_SZ 4
#define S_SZ 4096
#define D_SZ 1024
#define ELEMS_MAT ((size_t)B_SZ * S_SZ * D_SZ)   // 16,777,216

// ---- workspace layout (ushort elems), footprint <= proven 174 MB ----
#define OFF_Q  ((size_t)0)
#define OFF_K  (ELEMS_MAT)
#define OFF_VT (2 * ELEMS_MAT)
#define ZONE   (3 * ELEMS_MAT)
#define OFF_XB (ZONE)
#define OFF_WT (ZONE + 2 * ELEMS_MAT)
#define OFF_S  (ZONE)                             // aliases xb+Wt (dead by then)
#define S_BATCH ((size_t)8912896)                 // 136 tiles * 256*256
#define OFF_LP (ZONE + 4 * S_BATCH)               // [17][16384] f32 sumexp partials

#define MFMA16(a, b, c) __builtin_amdgcn_mfma_f32_16x16x32_bf16((a), (b), (c), 0, 0, 0)

static __device__ __forceinline__ unsigned short f2bf(float f) {
  __bf16 h = (__bf16)f;
  return __builtin_bit_cast(unsigned short, h);
}
static __device__ __forceinline__ float Ef(float x) {   // e^x via v_exp_f32
  return __builtin_exp2f(x * 1.44269504f);
}

static __device__ __forceinline__ void async_lds16(const void* g, void* l) {
  __builtin_amdgcn_global_load_lds((__attribute__((address_space(1))) void*)g,
                                   (__attribute__((address_space(3))) void*)l, 16, 0, 0);
}

// ---------------- cast x (fp32 -> bf16) ----------------
__global__ void cast_x_kernel(const float* __restrict__ x, unsigned short* __restrict__ xb) {
  size_t i = ((size_t)blockIdx.x * 256 + threadIdx.x) * 8;
  f32x4 a = *(const f32x4*)(x + i);
  f32x4 b = *(const f32x4*)(x + i + 4);
  bf16x8 o;
  o[0] = (__bf16)a[0]; o[1] = (__bf16)a[1]; o[2] = (__bf16)a[2]; o[3] = (__bf16)a[3];
  o[4] = (__bf16)b[0]; o[5] = (__bf16)b[1]; o[6] = (__bf16)b[2]; o[7] = (__bf16)b[3];
  *(bf16x8*)(xb + i) = o;
}

// ---------------- transpose-cast weights: Wt[n][k] = bf16(W[k][n]); Wt = [3072][1024] ----------------
__global__ void cast_wt_kernel(const float* __restrict__ Wq, const float* __restrict__ Wk,
                               const float* __restrict__ Wv, unsigned short* __restrict__ Wt) {
  __shared__ float tl[64][65];
  const float* W = blockIdx.z == 0 ? Wq : (blockIdx.z == 1 ? Wk : Wv);
  unsigned short* out = Wt + (size_t)blockIdx.z * (size_t)D_SZ * (size_t)D_SZ;
  const int k0 = blockIdx.x * 64, n0 = blockIdx.y * 64;
  const int t = threadIdx.x;
  for (int i = t; i < 4096; i += 256) {
    int r = i >> 6, c = i & 63;
    tl[r][c] = W[(size_t)(k0 + r) * D_SZ + n0 + c];
  }
  __syncthreads();
  for (int i = t; i < 4096; i += 256) {
    int r = i >> 6, c = i & 63;
    out[(size_t)(n0 + r) * D_SZ + k0 + c] = f2bf(tl[c][r]);
  }
}

// ================= phase-pipelined GEMM (T2+T3+T4+T5), proven r7/r9/r11 =================
// LDS half-tile: [rows][32 bf16] (64 B/row), 16-B slots, swizzle: slot ^= (row>>1)&3.
static __device__ __forceinline__ bf16x8 lds_frag(const char* half, int r, int hi) {
  return *(const bf16x8*)(half + r * 64 + ((hi * 16) ^ (((r >> 1) & 3) << 4)));
}

static __device__ __forceinline__ void stage_half256(const char* src, size_t ld, char* lds, int tid) {
#pragma unroll
  for (int it = 0; it < 2; ++it) {
    int i = it * 512 + tid;
    int row = i >> 2;
    int s = (i & 3) ^ ((row >> 1) & 3);
    async_lds16(src + (size_t)row * ld + s * 16, lds + i * 16);
  }
}
static __device__ __forceinline__ void stage_half128(const char* src, size_t ld, char* lds, int tid) {
  int row = tid >> 2;
  int s = (tid & 3) ^ ((row >> 1) & 3);
  async_lds16(src + (size_t)row * ld + s * 16, lds + tid * 16);
}

// ---- 256x256xBK64, 8 waves (2M x 4N), 4 phases/K-tile (race-free, r7) ----
static __device__ __forceinline__ void mainloop8p(const char* A, size_t lda,
                                                  const char* B, size_t ldb, int NT,
                                                  char sm[2][2][2][16384],
                                                  int tid, f32x4 acc[8][4]) {
  const int lane = tid & 63, w = tid >> 6;
  const int wm = w >> 2, wn = w & 3, lr = lane & 15, hi = lane >> 4;
  stage_half256(A,      lda, sm[0][0][0], tid);
  stage_half256(B,      ldb, sm[0][1][0], tid);
  stage_half256(A + 64, lda, sm[0][0][1], tid);
  stage_half256(B + 64, ldb, sm[0][1][1], tid);
  asm volatile("s_waitcnt vmcnt(4)" ::: "memory");
  __builtin_amdgcn_s_barrier();
  for (int t = 0; t < NT; ++t) {
    const int d = t & 1;
    const char* At1 = A + (size_t)(t + 1) * 128;
    const char* Bt1 = B + (size_t)(t + 1) * 128;
    const bool pre = (t + 1 < NT);
    bf16x8 af[4], bfr[4];
    // P1: half0, qm=0
#pragma unroll
    for (int g = 0; g < 4; ++g) bfr[g] = lds_frag(sm[d][1][0], wn * 64 + g * 16 + lr, hi);
#pragma unroll
    for (int f = 0; f < 4; ++f) af[f] = lds_frag(sm[d][0][0], wm * 128 + f * 16 + lr, hi);
    if (pre) stage_half256(At1, lda, sm[d ^ 1][0][0], tid);
    __builtin_amdgcn_s_barrier();
    asm volatile("s_waitcnt lgkmcnt(0)" ::: "memory");
    __builtin_amdgcn_s_setprio(1);
#pragma unroll
    for (int f = 0; f < 4; ++f)
#pragma unroll
      for (int g = 0; g < 4; ++g) acc[f][g] = MFMA16(af[f], bfr[g], acc[f][g]);
    __builtin_amdgcn_s_setprio(0);
    __builtin_amdgcn_s_barrier();
    // P2: half0, qm=1
#pragma unroll
    for (int f = 0; f < 4; ++f) af[f] = lds_frag(sm[d][0][0], wm * 128 + 64 + f * 16 + lr, hi);
    if (pre) stage_half256(Bt1, ldb, sm[d ^ 1][1][0], tid);
    __builtin_amdgcn_s_barrier();
    asm volatile("s_waitcnt lgkmcnt(0)" ::: "memory");
    __builtin_amdgcn_s_setprio(1);
#pragma unroll
    for (int f = 0; f < 4; ++f)
#pragma unroll
      for (int g = 0; g < 4; ++g) acc[4 + f][g] = MFMA16(af[f], bfr[g], acc[4 + f][g]);
    __builtin_amdgcn_s_setprio(0);
    if (pre) asm volatile("s_waitcnt vmcnt(4)" ::: "memory");
    else     asm volatile("s_waitcnt vmcnt(0)" ::: "memory");
    __builtin_amdgcn_s_barrier();
    // P3: half1, qm=0
#pragma unroll
    for (int g = 0; g < 4; ++g) bfr[g] = lds_frag(sm[d][1][1], wn * 64 + g * 16 + lr, hi);
#pragma unroll
    for (int f = 0; f < 4; ++f) af[f] = lds_frag(sm[d][0][1], wm * 128 + f * 16 + lr, hi);
    if (pre) stage_half256(At1 + 64, lda, sm[d ^ 1][0][1], tid);
    __builtin_amdgcn_s_barrier();
    asm volatile("s_waitcnt lgkmcnt(0)" ::: "memory");
    __builtin_amdgcn_s_setprio(1);
#pragma unroll
    for (int f = 0; f < 4; ++f)
#pragma unroll
      for (int g = 0; g < 4; ++g) acc[f][g] = MFMA16(af[f], bfr[g], acc[f][g]);
    __builtin_amdgcn_s_setprio(0);
    __builtin_amdgcn_s_barrier();
    // P4: half1, qm=1
#pragma unroll
    for (int f = 0; f < 4; ++f) af[f] = lds_frag(sm[d][0][1], wm * 128 + 64 + f * 16 + lr, hi);
    if (pre) stage_half256(Bt1 + 64, ldb, sm[d ^ 1][1][1], tid);
    __builtin_amdgcn_s_barrier();
    asm volatile("s_waitcnt lgkmcnt(0)" ::: "memory");
    __builtin_amdgcn_s_setprio(1);
#pragma unroll
    for (int f = 0; f < 4; ++f)
#pragma unroll
      for (int g = 0; g < 4; ++g) acc[4 + f][g] = MFMA16(af[f], bfr[g], acc[4 + f][g]);
    __builtin_amdgcn_s_setprio(0);
    if (pre) asm volatile("s_waitcnt vmcnt(4)" ::: "memory");
    __builtin_amdgcn_s_barrier();
  }
}

// ---- BM=256 x BN=128 x BK=64, 8 waves (4M x 2N), 2 phases/K-tile (r7, race-free) ----
static __device__ __forceinline__ void mainloop2p128(const char* A, size_t lda,
                                                     const char* B, size_t ldb, int NT,
                                                     char smA[2][2][16384],
                                                     char smB[2][2][8192],
                                                     int tid, f32x4 acc[4][4]) {
  const int lane = tid & 63, w = tid >> 6;
  const int wm = w >> 1, wn = w & 1, lr = lane & 15, hi = lane >> 4;
  stage_half256(A,      lda, smA[0][0], tid);
  stage_half128(B,      ldb, smB[0][0], tid);
  stage_half256(A + 64, lda, smA[0][1], tid);
  stage_half128(B + 64, ldb, smB[0][1], tid);
  asm volatile("s_waitcnt vmcnt(3)" ::: "memory");
  __builtin_amdgcn_s_barrier();
  for (int t = 0; t < NT; ++t) {
    const int d = t & 1;
    const char* At1 = A + (size_t)(t + 1) * 128;
    const char* Bt1 = B + (size_t)(t + 1) * 128;
    const bool pre = (t + 1 < NT);
    bf16x8 af[4], bfr[4];
    // P1: kk=0
#pragma unroll
    for (int g = 0; g < 4; ++g) bfr[g] = lds_frag(smB[d][0], wn * 64 + g * 16 + lr, hi);
#pragma unroll
    for (int f = 0; f < 4; ++f) af[f] = lds_frag(smA[d][0], wm * 64 + f * 16 + lr, hi);
    if (pre) { stage_half256(At1, lda, smA[d ^ 1][0], tid); stage_half128(Bt1, ldb, smB[d ^ 1][0], tid); }
    __builtin_amdgcn_s_barrier();
    asm volatile("s_waitcnt lgkmcnt(0)" ::: "memory");
    __builtin_amdgcn_s_setprio(1);
#pragma unroll
    for (int f = 0; f < 4; ++f)
#pragma unroll
      for (int g = 0; g < 4; ++g) acc[f][g] = MFMA16(af[f], bfr[g], acc[f][g]);
    __builtin_amdgcn_s_setprio(0);
    if (pre) asm volatile("s_waitcnt vmcnt(3)" ::: "memory");
    else     asm volatile("s_waitcnt vmcnt(0)" ::: "memory");
    __builtin_amdgcn_s_barrier();
    // P2: kk=1
#pragma unroll
    for (int g = 0; g < 4; ++g) bfr[g] = lds_frag(smB[d][1], wn * 64 + g * 16 + lr, hi);
#pragma unroll
    for (int f = 0; f < 4; ++f) af[f] = lds_frag(smA[d][1], wm * 64 + f * 16 + lr, hi);
    if (pre) { stage_half256(At1 + 64, lda, smA[d ^ 1][1], tid); stage_half128(Bt1 + 64, ldb, smB[d ^ 1][1], tid); }
    __builtin_amdgcn_s_barrier();
    asm volatile("s_waitcnt lgkmcnt(0)" ::: "memory");
    __builtin_amdgcn_s_setprio(1);
#pragma unroll
    for (int f = 0; f < 4; ++f)
#pragma unroll
      for (int g = 0; g < 4; ++g) acc[f][g] = MFMA16(af[f], bfr[g], acc[f][g]);
    __builtin_amdgcn_s_setprio(0);
    if (pre) asm volatile("s_waitcnt vmcnt(3)" ::: "memory");
    __builtin_amdgcn_s_barrier();
  }
}

// ---------------- QKV: [16384,1024] x [1024,3072]; V written transposed ----------------
__global__ __launch_bounds__(512, 2) void gemm_qkv256(const unsigned short* __restrict__ xb,
                                                      const unsigned short* __restrict__ Wt,
                                                      unsigned short* __restrict__ Q,
                                                      unsigned short* __restrict__ K,
                                                      unsigned short* __restrict__ Vt) {
  __shared__ char sm[2][2][2][16384];
  const int tid = threadIdx.x;
  f32x4 acc[8][4];
  {
    const f32x4 z4 = {0.f, 0.f, 0.f, 0.f};
#pragma unroll
    for (int f = 0; f < 8; ++f)
#pragma unroll
      for (int g = 0; g < 4; ++g) acc[f][g] = z4;
  }
  const int bid = blockIdx.x;
  const int sw = (bid & 7) * 96 + (bid >> 3);   // XCD swizzle (768 = 8*96)
  const int mt = sw / 12, nt = sw % 12;         // 12 consecutive (one XCD) share A panel
  const char* A = (const char*)xb + (size_t)mt * 256 * 2048;
  const char* Bp = (const char*)Wt + (size_t)nt * 256 * 2048;
  mainloop8p(A, 2048, Bp, 2048, 16, sm, tid, acc);
  const int lane = tid & 63, w = tid >> 6;
  const int wm = w >> 2, wn = w & 3;
  const int lr = lane & 15, hi = lane >> 4;
  if (nt < 8) {
    unsigned short* Out = (nt >> 2) == 0 ? Q : K;
    const int nb = (nt & 3) * 256;
#pragma unroll
    for (int f = 0; f < 8; ++f)
#pragma unroll
      for (int g = 0; g < 4; ++g)
#pragma unroll
        for (int j = 0; j < 4; ++j) {
          const int m = mt * 256 + wm * 128 + f * 16 + hi * 4 + j;
          const int n = nb + wn * 64 + g * 16 + lr;
          Out[(size_t)m * D_SZ + n] = f2bf(acc[f][g][j]);
        }
  } else {
    // V: write transposed Vt[b][d][s]; 4 consecutive s per store (8 B)
#pragma unroll
    for (int f = 0; f < 8; ++f)
#pragma unroll
      for (int g = 0; g < 4; ++g) {
        const int m = mt * 256 + wm * 128 + f * 16 + hi * 4;
        const int n = (nt - 8) * 256 + wn * 64 + g * 16 + lr;
        const int b = m >> 12, s = m & 4095;
        ushort4 pk;
        pk.x = f2bf(acc[f][g][0]); pk.y = f2bf(acc[f][g][1]);
        pk.z = f2bf(acc[f][g][2]); pk.w = f2bf(acc[f][g][3]);
        *(ushort4*)(Vt + (size_t)b * (D_SZ * S_SZ) + (size_t)n * S_SZ + s) = pk;
      }
  }
}

// ---------------- S-pass, mixed granularity: 64 half-tiles (first) + 512 full tiles ----
// P' = exp((QK^T)/32) masked; per-row sumexp partials into lp[J] (halves: odd->slot16 atomic).
__global__ __launch_bounds__(512, 2) void s_gemm_mixed(const unsigned short* __restrict__ Q,
                                                       const unsigned short* __restrict__ K,
                                                       unsigned short* __restrict__ Sp,
                                                       float* __restrict__ lp) {
  __shared__ char sm[2][2][2][16384];
  const int tid = threadIdx.x;
  const int bid = blockIdx.x;
  const int lane = tid & 63, w = tid >> 6;
  const int lr = lane & 15, hi = lane >> 4;

  if (bid < 64) {
    // ======== half-tile path: BN=128, tiles 512..543 (batch 3, I>=13) ========
    char (*smA)[2][16384] = (char (*)[2][16384])sm;
    char (*smB)[2][8192]  = (char (*)[2][8192])((char*)sm + 65536);
    const int hid = (bid & 7) * 8 + (bid >> 3);     // bijective, xcd = bid&7
    const int t = 104 + (hid >> 1);                 // tile-in-batch3: 104..135
    const int parity = hid & 1;
    int I = 13;
    while ((I + 1) * (I + 2) / 2 <= t) ++I;
    const int J = t - I * (I + 1) / 2;
    const int Jh = 2 * J + parity;
    const int b = 3;
    f32x4 acc[4][4];
    {
      const f32x4 z4 = {0.f, 0.f, 0.f, 0.f};
#pragma unroll
      for (int f = 0; f < 4; ++f)
#pragma unroll
        for (int g = 0; g < 4; ++g) acc[f][g] = z4;
    }
    const char* A = (const char*)Q + ((size_t)b * S_SZ + (size_t)I * 256) * 2048;
    const char* Bp = (const char*)K + ((size_t)b * S_SZ + (size_t)Jh * 128) * 2048;
    mainloop2p128(A, 2048, Bp, 2048, 16, smA, smB, tid, acc);
    const int wm = w >> 1, wn = w & 1;
    const int L = (I + 1) * 256;
    unsigned short* So = Sp + (size_t)b * S_BATCH + (size_t)(I * (I + 1) / 2) * 65536;
    float* shl = (float*)smB;          // 2 KB scratch, loop drained
    __syncthreads();
#pragma unroll
    for (int f = 0; f < 4; ++f) {
#pragma unroll
      for (int j = 0; j < 4; ++j) {
        const int m = wm * 64 + f * 16 + hi * 4 + j;
        float se = 0.f;
#pragma unroll
        for (int g = 0; g < 4; ++g) {
          const int nG = Jh * 128 + wn * 64 + g * 16 + lr;
          float v = acc[f][g][j] * 0.03125f;
          if (nG > I * 256 + m) v = -1e30f;
          float ev = Ef(v);
          So[(size_t)m * L + nG] = f2bf(ev);
          se += ev;
        }
        se += __shfl_xor(se, 1);
        se += __shfl_xor(se, 2);
        se += __shfl_xor(se, 4);
        se += __shfl_xor(se, 8);
        if (lr == 0) shl[wn * 256 + m] = se;
      }
    }
    __syncthreads();
    if (tid < 256) {
      float ll = shl[tid] + shl[256 + tid];
      const int r = b * 4096 + I * 256 + tid;
      if (parity == 0) lp[J * 16384 + r] = ll;
      else atomicAdd(lp + 16 * 16384 + r, ll);
    }
  } else {
    // ======== full-tile path: 256x256, tile ids 0..511 ========
    f32x4 acc[8][4];
    {
      const f32x4 z4 = {0.f, 0.f, 0.f, 0.f};
#pragma unroll
      for (int f = 0; f < 8; ++f)
#pragma unroll
        for (int g = 0; g < 4; ++g) acc[f][g] = z4;
    }
    const int fid = bid - 64;
    const int sw = (fid & 7) * 64 + (fid >> 3);   // bijective over 512
    const int b = sw / 136;
    const int tile = sw % 136;
    int I = (int)((sqrtf(8.0f * tile + 1.0f) - 1.0f) * 0.5f);
    while ((I + 1) * (I + 2) / 2 <= tile) ++I;
    while (I * (I + 1) / 2 > tile) --I;
    const int J = tile - I * (I + 1) / 2;
    const char* A = (const char*)Q + ((size_t)b * S_SZ + (size_t)I * 256) * 2048;
    const char* Bp = (const char*)K + ((size_t)b * S_SZ + (size_t)J * 256) * 2048;
    mainloop8p(A, 2048, Bp, 2048, 16, sm, tid, acc);
    const int wm = w >> 2, wn = w & 3;
    const int L = (I + 1) * 256;
    unsigned short* So = Sp + (size_t)b * S_BATCH + (size_t)(I * (I + 1) / 2) * 65536;
    float* shl = (float*)sm;           // [4 wn][256 rows] partials (loop drained)
    __syncthreads();
#pragma unroll
    for (int f = 0; f < 8; ++f) {
#pragma unroll
      for (int j = 0; j < 4; ++j) {
        const int m = wm * 128 + f * 16 + hi * 4 + j;
        float se = 0.f;
#pragma unroll
        for (int g = 0; g < 4; ++g) {
          const int n = J * 256 + wn * 64 + g * 16 + lr;
          float v = acc[f][g][j] * 0.03125f;
          if (n > I * 256 + m) v = -1e30f;
          float ev = Ef(v);
          So[(size_t)m * L + n] = f2bf(ev);
          se += ev;
        }
        se += __shfl_xor(se, 1);
        se += __shfl_xor(se, 2);
        se += __shfl_xor(se, 4);
        se += __shfl_xor(se, 8);
        if (lr == 0) shl[wn * 256 + m] = se;
      }
    }
    __syncthreads();
    if (tid < 256) {
      float ll = shl[tid] + shl[256 + tid] + shl[512 + tid] + shl[768 + tid];
      lp[J * 16384 + b * 4096 + I * 256 + tid] = ll;
    }
  }
}

// ---------------- sum partials -> slot0 holds 1/l per row ----------------
__global__ __launch_bounds__(256) void sum_stats(float* __restrict__ lp) {
  const int r = blockIdx.x * 256 + threadIdx.x;    // 16384 rows
  const int I = (r & 4095) >> 8;
  float l = 0.f;
  for (int J = 0; J <= I; ++J) l += lp[J * 16384 + r];
  if (r >= 15616) l += lp[16 * 16384 + r];         // b=3, I>=13: odd-half partials
  lp[r] = 1.0f / l;
}

// ---------------- O = P' V * rl, paired row-blocks (68 K-steps, uniform) ----------------
__global__ __launch_bounds__(512, 2) void pv_bal(const unsigned short* __restrict__ Sp,
                                                 const unsigned short* __restrict__ Vt,
                                                 const float* __restrict__ lp,
                                                 float* __restrict__ out) {
  __shared__ char smA[2][2][16384];
  __shared__ char smB[2][2][8192];
  const int tid = threadIdx.x;
  const int bid = blockIdx.x;
  const int sw = (bid & 7) * 32 + (bid >> 3);   // 256 = 8*32, bijective
  const int p = sw >> 5, b = (sw >> 3) & 3, nt = sw & 7;
  const int lane = tid & 63, w = tid >> 6;
  const int wm = w >> 1, wn = w & 1;
  const int lr = lane & 15, hi = lane >> 4;
  f32x4 acc[4][4];
#pragma unroll
  for (int half = 0; half < 2; ++half) {
    const int I = half ? (15 - p) : p;
    {
      const f32x4 z4 = {0.f, 0.f, 0.f, 0.f};
#pragma unroll
      for (int f = 0; f < 4; ++f)
#pragma unroll
        for (int g = 0; g < 4; ++g) acc[f][g] = z4;
    }
    const char* A = (const char*)(Sp + (size_t)b * S_BATCH + (size_t)(I * (I + 1) / 2) * 65536);
    const size_t lda = (size_t)(I + 1) * 512;   // bytes
    const char* Bp = (const char*)Vt + ((size_t)b * D_SZ + (size_t)nt * 128) * (S_SZ * 2);
    mainloop2p128(A, lda, Bp, S_SZ * 2, (I + 1) * 4, smA, smB, tid, acc);
#pragma unroll
    for (int f = 0; f < 4; ++f)
#pragma unroll
      for (int j = 0; j < 4; ++j) {
        const int m = wm * 64 + f * 16 + hi * 4 + j;
        const float rl = lp[b * 4096 + I * 256 + m];
#pragma unroll
        for (int g = 0; g < 4; ++g) {
          const int n = nt * 128 + wn * 64 + g * 16 + lr;
          out[((size_t)b * S_SZ + (size_t)I * 256 + m) * D_SZ + n] = acc[f][g][j] * rl;
        }
      }
    __syncthreads();
  }
}

extern "C" void kernel_launch(void* const* d_in, const int* in_sizes, int n_in,
                              void* d_out, int out_size, void* d_ws, size_t ws_size,
                              hipStream_t stream) {
  (void)in_sizes; (void)n_in; (void)out_size; (void)ws_size;
  const float* x  = (const float*)d_in[0];
  const float* Wq = (const float*)d_in[1];
  const float* Wk = (const float*)d_in[2];
  const float* Wv = (const float*)d_in[3];
  float* out = (float*)d_out;
  unsigned short* ws = (unsigned short*)d_ws;
  float* lp = (float*)(ws + OFF_LP);

  cast_x_kernel<<<8192, 256, 0, stream>>>(x, ws + OFF_XB);
  cast_wt_kernel<<<dim3(16, 16, 3), 256, 0, stream>>>(Wq, Wk, Wv, ws + OFF_WT);
  gemm_qkv256<<<768, 512, 0, stream>>>(ws + OFF_XB, ws + OFF_WT,
                                       ws + OFF_Q, ws + OFF_K, ws + OFF_VT);
  hipMemsetAsync(lp + 16 * 16384, 0, 16384 * sizeof(float), stream);  // slot16 accum
  s_gemm_mixed<<<576, 512, 0, stream>>>(ws + OFF_Q, ws + OFF_K, ws + OFF_S, lp);
  sum_stats<<<64, 256, 0, stream>>>(lp);
  pv_bal<<<256, 512, 0, stream>>>(ws + OFF_S, ws + OFF_VT, lp, out);
}

// Round 14
// 331.575 us; speedup vs baseline: 1.1320x; 1.0303x over previous
//
#include <hip/hip_runtime.h>

typedef __bf16 bf16x8 __attribute__((ext_vector_type(8)));
typedef float f32x4 __attribute__((ext_vector_type(4)));

#define B_SZ 4
#define S_SZ 4096
#define D_SZ 1024
#define ELEMS_MAT ((size_t)B_SZ * S_SZ * D_SZ)   // 16,777,216

// ---- workspace layout (ushort elems), footprint <= proven 174 MB ----
#define OFF_Q  ((size_t)0)
#define OFF_K  (ELEMS_MAT)
#define OFF_VT (2 * ELEMS_MAT)
#define ZONE   (3 * ELEMS_MAT)
#define OFF_XB (ZONE)
#define OFF_WT (ZONE + 2 * ELEMS_MAT)
#define OFF_S  (ZONE)                             // aliases xb+Wt (dead by then)
#define S_BATCH ((size_t)8912896)                 // 136 tiles * 256*256
#define OFF_LP (ZONE + 4 * S_BATCH)               // [17][16384] f32 sumexp partials

#define MFMA16(a, b, c) __builtin_amdgcn_mfma_f32_16x16x32_bf16((a), (b), (c), 0, 0, 0)

static __device__ __forceinline__ unsigned short f2bf(float f) {
  __bf16 h = (__bf16)f;
  return __builtin_bit_cast(unsigned short, h);
}
static __device__ __forceinline__ float Ef(float x) {   // e^x via v_exp_f32
  return __builtin_exp2f(x * 1.44269504f);
}

static __device__ __forceinline__ void async_lds16(const void* g, void* l) {
  __builtin_amdgcn_global_load_lds((__attribute__((address_space(1))) void*)g,
                                   (__attribute__((address_space(3))) void*)l, 16, 0, 0);
}

// ---------------- fused cast: x (fp32->bf16) + weight transpose-cast ----------------
// bid < 8192: cast_x chunk. bid >= 8192: one 64x64 transpose tile of Wq/Wk/Wv.
__global__ void cast_fused_kernel(const float* __restrict__ x, unsigned short* __restrict__ xb,
                                  const float* __restrict__ Wq, const float* __restrict__ Wk,
                                  const float* __restrict__ Wv, unsigned short* __restrict__ Wt) {
  __shared__ float tl[64][65];
  const int bid = blockIdx.x;
  const int t = threadIdx.x;
  if (bid < 8192) {
    size_t i = ((size_t)bid * 256 + t) * 8;
    f32x4 a = *(const f32x4*)(x + i);
    f32x4 b = *(const f32x4*)(x + i + 4);
    bf16x8 o;
    o[0] = (__bf16)a[0]; o[1] = (__bf16)a[1]; o[2] = (__bf16)a[2]; o[3] = (__bf16)a[3];
    o[4] = (__bf16)b[0]; o[5] = (__bf16)b[1]; o[6] = (__bf16)b[2]; o[7] = (__bf16)b[3];
    *(bf16x8*)(xb + i) = o;
  } else {
    const int cid = bid - 8192;              // 0..767
    const int z = cid >> 8;                  // 0..2
    const int rem = cid & 255;
    const int bx = rem & 15, by = rem >> 4;
    const float* W = z == 0 ? Wq : (z == 1 ? Wk : Wv);
    unsigned short* out = Wt + (size_t)z * (size_t)D_SZ * (size_t)D_SZ;
    const int k0 = bx * 64, n0 = by * 64;
    for (int i = t; i < 4096; i += 256) {
      int r = i >> 6, c = i & 63;
      tl[r][c] = W[(size_t)(k0 + r) * D_SZ + n0 + c];
    }
    __syncthreads();
    for (int i = t; i < 4096; i += 256) {
      int r = i >> 6, c = i & 63;
      out[(size_t)(n0 + r) * D_SZ + k0 + c] = f2bf(tl[c][r]);
    }
  }
}

// ================= phase-pipelined GEMM (T2+T3+T4+T5), proven r7/r9/r11/r13 =================
// LDS half-tile: [rows][32 bf16] (64 B/row), 16-B slots, swizzle: slot ^= (row>>1)&3.
static __device__ __forceinline__ bf16x8 lds_frag(const char* half, int r, int hi) {
  return *(const bf16x8*)(half + r * 64 + ((hi * 16) ^ (((r >> 1) & 3) << 4)));
}

static __device__ __forceinline__ void stage_half256(const char* src, size_t ld, char* lds, int tid) {
#pragma unroll
  for (int it = 0; it < 2; ++it) {
    int i = it * 512 + tid;
    int row = i >> 2;
    int s = (i & 3) ^ ((row >> 1) & 3);
    async_lds16(src + (size_t)row * ld + s * 16, lds + i * 16);
  }
}
static __device__ __forceinline__ void stage_half128(const char* src, size_t ld, char* lds, int tid) {
  int row = tid >> 2;
  int s = (tid & 3) ^ ((row >> 1) & 3);
  async_lds16(src + (size_t)row * ld + s * 16, lds + tid * 16);
}

// ---- 256x256xBK64, 8 waves (2M x 4N), 4 phases/K-tile (race-free, r7) ----
static __device__ __forceinline__ void mainloop8p(const char* A, size_t lda,
                                                  const char* B, size_t ldb, int NT,
                                                  char sm[2][2][2][16384],
                                                  int tid, f32x4 acc[8][4]) {
  const int lane = tid & 63, w = tid >> 6;
  const int wm = w >> 2, wn = w & 3, lr = lane & 15, hi = lane >> 4;
  stage_half256(A,      lda, sm[0][0][0], tid);
  stage_half256(B,      ldb, sm[0][1][0], tid);
  stage_half256(A + 64, lda, sm[0][0][1], tid);
  stage_half256(B + 64, ldb, sm[0][1][1], tid);
  asm volatile("s_waitcnt vmcnt(4)" ::: "memory");
  __builtin_amdgcn_s_barrier();
  for (int t = 0; t < NT; ++t) {
    const int d = t & 1;
    const char* At1 = A + (size_t)(t + 1) * 128;
    const char* Bt1 = B + (size_t)(t + 1) * 128;
    const bool pre = (t + 1 < NT);
    bf16x8 af[4], bfr[4];
    // P1: half0, qm=0
#pragma unroll
    for (int g = 0; g < 4; ++g) bfr[g] = lds_frag(sm[d][1][0], wn * 64 + g * 16 + lr, hi);
#pragma unroll
    for (int f = 0; f < 4; ++f) af[f] = lds_frag(sm[d][0][0], wm * 128 + f * 16 + lr, hi);
    if (pre) stage_half256(At1, lda, sm[d ^ 1][0][0], tid);
    __builtin_amdgcn_s_barrier();
    asm volatile("s_waitcnt lgkmcnt(0)" ::: "memory");
    __builtin_amdgcn_s_setprio(1);
#pragma unroll
    for (int f = 0; f < 4; ++f)
#pragma unroll
      for (int g = 0; g < 4; ++g) acc[f][g] = MFMA16(af[f], bfr[g], acc[f][g]);
    __builtin_amdgcn_s_setprio(0);
    __builtin_amdgcn_s_barrier();
    // P2: half0, qm=1
#pragma unroll
    for (int f = 0; f < 4; ++f) af[f] = lds_frag(sm[d][0][0], wm * 128 + 64 + f * 16 + lr, hi);
    if (pre) stage_half256(Bt1, ldb, sm[d ^ 1][1][0], tid);
    __builtin_amdgcn_s_barrier();
    asm volatile("s_waitcnt lgkmcnt(0)" ::: "memory");
    __builtin_amdgcn_s_setprio(1);
#pragma unroll
    for (int f = 0; f < 4; ++f)
#pragma unroll
      for (int g = 0; g < 4; ++g) acc[4 + f][g] = MFMA16(af[f], bfr[g], acc[4 + f][g]);
    __builtin_amdgcn_s_setprio(0);
    if (pre) asm volatile("s_waitcnt vmcnt(4)" ::: "memory");
    else     asm volatile("s_waitcnt vmcnt(0)" ::: "memory");
    __builtin_amdgcn_s_barrier();
    // P3: half1, qm=0
#pragma unroll
    for (int g = 0; g < 4; ++g) bfr[g] = lds_frag(sm[d][1][1], wn * 64 + g * 16 + lr, hi);
#pragma unroll
    for (int f = 0; f < 4; ++f) af[f] = lds_frag(sm[d][0][1], wm * 128 + f * 16 + lr, hi);
    if (pre) stage_half256(At1 + 64, lda, sm[d ^ 1][0][1], tid);
    __builtin_amdgcn_s_barrier();
    asm volatile("s_waitcnt lgkmcnt(0)" ::: "memory");
    __builtin_amdgcn_s_setprio(1);
#pragma unroll
    for (int f = 0; f < 4; ++f)
#pragma unroll
      for (int g = 0; g < 4; ++g) acc[f][g] = MFMA16(af[f], bfr[g], acc[f][g]);
    __builtin_amdgcn_s_setprio(0);
    __builtin_amdgcn_s_barrier();
    // P4: half1, qm=1
#pragma unroll
    for (int f = 0; f < 4; ++f) af[f] = lds_frag(sm[d][0][1], wm * 128 + 64 + f * 16 + lr, hi);
    if (pre) stage_half256(Bt1 + 64, ldb, sm[d ^ 1][1][1], tid);
    __builtin_amdgcn_s_barrier();
    asm volatile("s_waitcnt lgkmcnt(0)" ::: "memory");
    __builtin_amdgcn_s_setprio(1);
#pragma unroll
    for (int f = 0; f < 4; ++f)
#pragma unroll
      for (int g = 0; g < 4; ++g) acc[4 + f][g] = MFMA16(af[f], bfr[g], acc[4 + f][g]);
    __builtin_amdgcn_s_setprio(0);
    if (pre) asm volatile("s_waitcnt vmcnt(4)" ::: "memory");
    __builtin_amdgcn_s_barrier();
  }
}

// ---- BM=256 x BN=128 x BK=64, 8 waves (4M x 2N), 2 phases/K-tile (r7, race-free) ----
static __device__ __forceinline__ void mainloop2p128(const char* A, size_t lda,
                                                     const char* B, size_t ldb, int NT,
                                                     char smA[2][2][16384],
                                                     char smB[2][2][8192],
                                                     int tid, f32x4 acc[4][4]) {
  const int lane = tid & 63, w = tid >> 6;
  const int wm = w >> 1, wn = w & 1, lr = lane & 15, hi = lane >> 4;
  stage_half256(A,      lda, smA[0][0], tid);
  stage_half128(B,      ldb, smB[0][0], tid);
  stage_half256(A + 64, lda, smA[0][1], tid);
  stage_half128(B + 64, ldb, smB[0][1], tid);
  asm volatile("s_waitcnt vmcnt(3)" ::: "memory");
  __builtin_amdgcn_s_barrier();
  for (int t = 0; t < NT; ++t) {
    const int d = t & 1;
    const char* At1 = A + (size_t)(t + 1) * 128;
    const char* Bt1 = B + (size_t)(t + 1) * 128;
    const bool pre = (t + 1 < NT);
    bf16x8 af[4], bfr[4];
    // P1: kk=0
#pragma unroll
    for (int g = 0; g < 4; ++g) bfr[g] = lds_frag(smB[d][0], wn * 64 + g * 16 + lr, hi);
#pragma unroll
    for (int f = 0; f < 4; ++f) af[f] = lds_frag(smA[d][0], wm * 64 + f * 16 + lr, hi);
    if (pre) { stage_half256(At1, lda, smA[d ^ 1][0], tid); stage_half128(Bt1, ldb, smB[d ^ 1][0], tid); }
    __builtin_amdgcn_s_barrier();
    asm volatile("s_waitcnt lgkmcnt(0)" ::: "memory");
    __builtin_amdgcn_s_setprio(1);
#pragma unroll
    for (int f = 0; f < 4; ++f)
#pragma unroll
      for (int g = 0; g < 4; ++g) acc[f][g] = MFMA16(af[f], bfr[g], acc[f][g]);
    __builtin_amdgcn_s_setprio(0);
    if (pre) asm volatile("s_waitcnt vmcnt(3)" ::: "memory");
    else     asm volatile("s_waitcnt vmcnt(0)" ::: "memory");
    __builtin_amdgcn_s_barrier();
    // P2: kk=1
#pragma unroll
    for (int g = 0; g < 4; ++g) bfr[g] = lds_frag(smB[d][1], wn * 64 + g * 16 + lr, hi);
#pragma unroll
    for (int f = 0; f < 4; ++f) af[f] = lds_frag(smA[d][1], wm * 64 + f * 16 + lr, hi);
    if (pre) { stage_half256(At1 + 64, lda, smA[d ^ 1][1], tid); stage_half128(Bt1 + 64, ldb, smB[d ^ 1][1], tid); }
    __builtin_amdgcn_s_barrier();
    asm volatile("s_waitcnt lgkmcnt(0)" ::: "memory");
    __builtin_amdgcn_s_setprio(1);
#pragma unroll
    for (int f = 0; f < 4; ++f)
#pragma unroll
      for (int g = 0; g < 4; ++g) acc[f][g] = MFMA16(af[f], bfr[g], acc[f][g]);
    __builtin_amdgcn_s_setprio(0);
    if (pre) asm volatile("s_waitcnt vmcnt(3)" ::: "memory");
    __builtin_amdgcn_s_barrier();
  }
}

// ---------------- QKV: [16384,1024] x [1024,3072]; V written transposed ----------------
__global__ __launch_bounds__(512, 2) void gemm_qkv256(const unsigned short* __restrict__ xb,
                                                      const unsigned short* __restrict__ Wt,
                                                      unsigned short* __restrict__ Q,
                                                      unsigned short* __restrict__ K,
                                                      unsigned short* __restrict__ Vt) {
  __shared__ char sm[2][2][2][16384];
  const int tid = threadIdx.x;
  f32x4 acc[8][4];
  {
    const f32x4 z4 = {0.f, 0.f, 0.f, 0.f};
#pragma unroll
    for (int f = 0; f < 8; ++f)
#pragma unroll
      for (int g = 0; g < 4; ++g) acc[f][g] = z4;
  }
  const int bid = blockIdx.x;
  const int sw = (bid & 7) * 96 + (bid >> 3);   // XCD swizzle (768 = 8*96)
  const int mt = sw / 12, nt = sw % 12;         // 12 consecutive (one XCD) share A panel
  const char* A = (const char*)xb + (size_t)mt * 256 * 2048;
  const char* Bp = (const char*)Wt + (size_t)nt * 256 * 2048;
  mainloop8p(A, 2048, Bp, 2048, 16, sm, tid, acc);
  const int lane = tid & 63, w = tid >> 6;
  const int wm = w >> 2, wn = w & 3;
  const int lr = lane & 15, hi = lane >> 4;
  if (nt < 8) {
    unsigned short* Out = (nt >> 2) == 0 ? Q : K;
    const int nb = (nt & 3) * 256;
#pragma unroll
    for (int f = 0; f < 8; ++f)
#pragma unroll
      for (int g = 0; g < 4; ++g)
#pragma unroll
        for (int j = 0; j < 4; ++j) {
          const int m = mt * 256 + wm * 128 + f * 16 + hi * 4 + j;
          const int n = nb + wn * 64 + g * 16 + lr;
          Out[(size_t)m * D_SZ + n] = f2bf(acc[f][g][j]);
        }
  } else {
    // V: write transposed Vt[b][d][s]; 4 consecutive s per store (8 B)
#pragma unroll
    for (int f = 0; f < 8; ++f)
#pragma unroll
      for (int g = 0; g < 4; ++g) {
        const int m = mt * 256 + wm * 128 + f * 16 + hi * 4;
        const int n = (nt - 8) * 256 + wn * 64 + g * 16 + lr;
        const int b = m >> 12, s = m & 4095;
        ushort4 pk;
        pk.x = f2bf(acc[f][g][0]); pk.y = f2bf(acc[f][g][1]);
        pk.z = f2bf(acc[f][g][2]); pk.w = f2bf(acc[f][g][3]);
        *(ushort4*)(Vt + (size_t)b * (D_SZ * S_SZ) + (size_t)n * S_SZ + s) = pk;
      }
  }
}

// ---------------- S-pass, mixed granularity: 64 half-tiles (first) + 512 full tiles ----
// P' = exp((QK^T)/32) masked; per-row sumexp partials into lp[J] (halves: odd->slot16 atomic).
__global__ __launch_bounds__(512, 2) void s_gemm_mixed(const unsigned short* __restrict__ Q,
                                                       const unsigned short* __restrict__ K,
                                                       unsigned short* __restrict__ Sp,
                                                       float* __restrict__ lp) {
  __shared__ char sm[2][2][2][16384];
  const int tid = threadIdx.x;
  const int bid = blockIdx.x;
  const int lane = tid & 63, w = tid >> 6;
  const int lr = lane & 15, hi = lane >> 4;

  if (bid < 64) {
    // ======== half-tile path: BN=128, tiles 512..543 (batch 3, I>=13) ========
    char (*smA)[2][16384] = (char (*)[2][16384])sm;
    char (*smB)[2][8192]  = (char (*)[2][8192])((char*)sm + 65536);
    const int hid = (bid & 7) * 8 + (bid >> 3);     // bijective, xcd = bid&7
    const int t = 104 + (hid >> 1);                 // tile-in-batch3: 104..135
    const int parity = hid & 1;
    int I = 13;
    while ((I + 1) * (I + 2) / 2 <= t) ++I;
    const int J = t - I * (I + 1) / 2;
    const int Jh = 2 * J + parity;
    const int b = 3;
    f32x4 acc[4][4];
    {
      const f32x4 z4 = {0.f, 0.f, 0.f, 0.f};
#pragma unroll
      for (int f = 0; f < 4; ++f)
#pragma unroll
        for (int g = 0; g < 4; ++g) acc[f][g] = z4;
    }
    const char* A = (const char*)Q + ((size_t)b * S_SZ + (size_t)I * 256) * 2048;
    const char* Bp = (const char*)K + ((size_t)b * S_SZ + (size_t)Jh * 128) * 2048;
    mainloop2p128(A, 2048, Bp, 2048, 16, smA, smB, tid, acc);
    const int wm = w >> 1, wn = w & 1;
    const int L = (I + 1) * 256;
    unsigned short* So = Sp + (size_t)b * S_BATCH + (size_t)(I * (I + 1) / 2) * 65536;
    float* shl = (float*)smB;          // 2 KB scratch, loop drained
    __syncthreads();
#pragma unroll
    for (int f = 0; f < 4; ++f) {
#pragma unroll
      for (int j = 0; j < 4; ++j) {
        const int m = wm * 64 + f * 16 + hi * 4 + j;
        float se = 0.f;
#pragma unroll
        for (int g = 0; g < 4; ++g) {
          const int nG = Jh * 128 + wn * 64 + g * 16 + lr;
          float v = acc[f][g][j] * 0.03125f;
          if (nG > I * 256 + m) v = -1e30f;
          float ev = Ef(v);
          So[(size_t)m * L + nG] = f2bf(ev);
          se += ev;
        }
        se += __shfl_xor(se, 1);
        se += __shfl_xor(se, 2);
        se += __shfl_xor(se, 4);
        se += __shfl_xor(se, 8);
        if (lr == 0) shl[wn * 256 + m] = se;
      }
    }
    __syncthreads();
    if (tid < 256) {
      float ll = shl[tid] + shl[256 + tid];
      const int r = b * 4096 + I * 256 + tid;
      if (parity == 0) lp[J * 16384 + r] = ll;
      else atomicAdd(lp + 16 * 16384 + r, ll);
    }
  } else {
    // ======== full-tile path: 256x256, tile ids 0..511 ========
    f32x4 acc[8][4];
    {
      const f32x4 z4 = {0.f, 0.f, 0.f, 0.f};
#pragma unroll
      for (int f = 0; f < 8; ++f)
#pragma unroll
        for (int g = 0; g < 4; ++g) acc[f][g] = z4;
    }
    const int fid = bid - 64;
    const int sw = (fid & 7) * 64 + (fid >> 3);   // bijective over 512
    const int b = sw / 136;
    const int tile = sw % 136;
    int I = (int)((sqrtf(8.0f * tile + 1.0f) - 1.0f) * 0.5f);
    while ((I + 1) * (I + 2) / 2 <= tile) ++I;
    while (I * (I + 1) / 2 > tile) --I;
    const int J = tile - I * (I + 1) / 2;
    const char* A = (const char*)Q + ((size_t)b * S_SZ + (size_t)I * 256) * 2048;
    const char* Bp = (const char*)K + ((size_t)b * S_SZ + (size_t)J * 256) * 2048;
    mainloop8p(A, 2048, Bp, 2048, 16, sm, tid, acc);
    const int wm = w >> 2, wn = w & 3;
    const int L = (I + 1) * 256;
    unsigned short* So = Sp + (size_t)b * S_BATCH + (size_t)(I * (I + 1) / 2) * 65536;
    float* shl = (float*)sm;           // [4 wn][256 rows] partials (loop drained)
    __syncthreads();
#pragma unroll
    for (int f = 0; f < 8; ++f) {
#pragma unroll
      for (int j = 0; j < 4; ++j) {
        const int m = wm * 128 + f * 16 + hi * 4 + j;
        float se = 0.f;
#pragma unroll
        for (int g = 0; g < 4; ++g) {
          const int n = J * 256 + wn * 64 + g * 16 + lr;
          float v = acc[f][g][j] * 0.03125f;
          if (n > I * 256 + m) v = -1e30f;
          float ev = Ef(v);
          So[(size_t)m * L + n] = f2bf(ev);
          se += ev;
        }
        se += __shfl_xor(se, 1);
        se += __shfl_xor(se, 2);
        se += __shfl_xor(se, 4);
        se += __shfl_xor(se, 8);
        if (lr == 0) shl[wn * 256 + m] = se;
      }
    }
    __syncthreads();
    if (tid < 256) {
      float ll = shl[tid] + shl[256 + tid] + shl[512 + tid] + shl[768 + tid];
      lp[J * 16384 + b * 4096 + I * 256 + tid] = ll;
    }
  }
}

// ---------------- O = P' V * rl, paired row-blocks; 1/l computed in prologue ----------------
__global__ __launch_bounds__(512, 2) void pv_bal(const unsigned short* __restrict__ Sp,
                                                 const unsigned short* __restrict__ Vt,
                                                 const float* __restrict__ lp,
                                                 float* __restrict__ out) {
  __shared__ char smA[2][2][16384];
  __shared__ char smB[2][2][8192];
  __shared__ float shrl[512];          // [0..255]: rows of I0=p; [256..511]: rows of I1=15-p
  const int tid = threadIdx.x;
  const int bid = blockIdx.x;
  const int sw = (bid & 7) * 32 + (bid >> 3);   // 256 = 8*32, bijective
  const int p = sw >> 5, b = (sw >> 3) & 3, nt = sw & 7;
  const int lane = tid & 63, w = tid >> 6;
  const int wm = w >> 1, wn = w & 1;
  const int lr = lane & 15, hi = lane >> 4;

  // prologue: per-row 1/l for this block's 512 rows (fused former sum_stats).
  // Loads are consumed by the ds_write below, so they retire before the
  // mainloop's counted vmcnt sequence begins.
  {
    const int Ith = tid < 256 ? p : (15 - p);
    const int r = b * 4096 + Ith * 256 + (tid & 255);
    float l = 0.f;
    for (int J = 0; J <= Ith; ++J) l += lp[J * 16384 + r];
    if (r >= 15616) l += lp[16 * 16384 + r];   // b=3, I>=13: odd-half partials
    shrl[tid] = 1.0f / l;
  }
  // visibility of shrl is guaranteed by the mainloop's internal barriers.

  f32x4 acc[4][4];
#pragma unroll
  for (int half = 0; half < 2; ++half) {
    const int I = half ? (15 - p) : p;
    {
      const f32x4 z4 = {0.f, 0.f, 0.f, 0.f};
#pragma unroll
      for (int f = 0; f < 4; ++f)
#pragma unroll
        for (int g = 0; g < 4; ++g) acc[f][g] = z4;
    }
    const char* A = (const char*)(Sp + (size_t)b * S_BATCH + (size_t)(I * (I + 1) / 2) * 65536);
    const size_t lda = (size_t)(I + 1) * 512;   // bytes
    const char* Bp = (const char*)Vt + ((size_t)b * D_SZ + (size_t)nt * 128) * (S_SZ * 2);
    mainloop2p128(A, lda, Bp, S_SZ * 2, (I + 1) * 4, smA, smB, tid, acc);
#pragma unroll
    for (int f = 0; f < 4; ++f)
#pragma unroll
      for (int j = 0; j < 4; ++j) {
        const int m = wm * 64 + f * 16 + hi * 4 + j;
        const float rl = shrl[half * 256 + m];
#pragma unroll
        for (int g = 0; g < 4; ++g) {
          const int n = nt * 128 + wn * 64 + g * 16 + lr;
          out[((size_t)b * S_SZ + (size_t)I * 256 + m) * D_SZ + n] = acc[f][g][j] * rl;
        }
      }
    __syncthreads();
  }
}

extern "C" void kernel_launch(void* const* d_in, const int* in_sizes, int n_in,
                              void* d_out, int out_size, void* d_ws, size_t ws_size,
                              hipStream_t stream) {
  (void)in_sizes; (void)n_in; (void)out_size; (void)ws_size;
  const float* x  = (const float*)d_in[0];
  const float* Wq = (const float*)d_in[1];
  const float* Wk = (const float*)d_in[2];
  const float* Wv = (const float*)d_in[3];
  float* out = (float*)d_out;
  unsigned short* ws = (unsigned short*)d_ws;
  float* lp = (float*)(ws + OFF_LP);

  cast_fused_kernel<<<8960, 256, 0, stream>>>(x, ws + OFF_XB, Wq, Wk, Wv, ws + OFF_WT);
  gemm_qkv256<<<768, 512, 0, stream>>>(ws + OFF_XB, ws + OFF_WT,
                                       ws + OFF_Q, ws + OFF_K, ws + OFF_VT);
  hipMemsetAsync(lp + 16 * 16384, 0, 16384 * sizeof(float), stream);  // slot16 accum
  s_gemm_mixed<<<576, 512, 0, stream>>>(ws + OFF_Q, ws + OFF_K, ws + OFF_S, lp);
  pv_bal<<<256, 512, 0, stream>>>(ws + OFF_S, ws + OFF_VT, lp, out);
}